// Round 7
// baseline (347.937 us; speedup 1.0000x reference)
//
#include <hip/hip_runtime.h>
#include <hip/hip_bf16.h>

// Gather backward / scatter-add:
//   out = zeros(50000, 1024); out[indices[i], :] += grad_last[i, :]
//
// R5 (memset + fill + gather, 3 launches): 145 µs; gather ~5.8 TB/s effective,
// remaining slack ~10 µs of dispatch overhead. R6's cooperative fuse never
// launched (all-zero output). This round: same fusion, but a hand-rolled
// device-scope barrier in a NORMAL launch with co-residency by construction:
//   - 1024 blocks x 256 thr, __launch_bounds__(256,4) => VGPR<=128 => >=4
//     blocks/CU => 1024-block capacity exactly; grid fills it.
//   - barrier: per-block atomicAdd arrival + acquire-load spin; two separate
//     counters (one per barrier use), zeroed by an 8 B memset (the only other
//     dispatch). __threadfence() release before arrival (cross-XCD safe).
//     0.2 s realtime timeout in the spin = anti-hang insurance.
//   - gather grid-stride loop prefetches the NEXT row's 64 B meta line while
//     current row's grad loads are in flight (fused loop loses R5's
//     block-turnover latency hiding; this restores it).

#define NCOLS 1024
#define C4 (NCOLS / 4)
#define CAP 15            // slots per 64B meta line (16 ints: cnt + 15 slots)
#define NBLK 1024
#define NTHR 256

typedef float f4 __attribute__((ext_vector_type(4)));

__device__ __forceinline__ void grid_bar(int* cnt) {
    __syncthreads();
    if (threadIdx.x == 0) {
        __threadfence();                       // release phase writes, device scope
        atomicAdd(cnt, 1);
        unsigned long long t0 = __builtin_amdgcn_s_memrealtime();
        while (__hip_atomic_load(cnt, __ATOMIC_ACQUIRE,
                                 __HIP_MEMORY_SCOPE_AGENT) < NBLK) {
            __builtin_amdgcn_s_sleep(2);
            // ~0.2s @100MHz realtime clock: never hit when all blocks resident;
            // prevents a hard hang if residency assumption ever breaks.
            if (__builtin_amdgcn_s_memrealtime() - t0 > 20000000ull) break;
        }
    }
    __syncthreads();
}

__global__ __launch_bounds__(NTHR, 4) void fused_kernel(
    const f4* __restrict__ grad, const int* __restrict__ idx,
    int* __restrict__ meta, int* __restrict__ ovf_list,
    int* __restrict__ ovf_cnt, int* __restrict__ bar,
    f4* __restrict__ out, int n_idx, int nrows) {
    int tid = threadIdx.x;
    int gtid = blockIdx.x * NTHR + tid;
    const int gstride = NBLK * NTHR;

    // ---- phase 0: zero meta (+ ovf_cnt) ----
    int n_int4 = nrows * 4;                // nrows*16 ints / 4
    int4 z = {0, 0, 0, 0};
    for (int i = gtid; i < n_int4; i += gstride) ((int4*)meta)[i] = z;
    if (gtid == 0) *ovf_cnt = 0;
    grid_bar(bar);

    // ---- phase 1: fill fixed-capacity buckets ----
    for (int i = gtid; i < n_idx; i += gstride) {
        int row = idx[i];
        int local = atomicAdd(&meta[(size_t)row * 16], 1);
        if (local < CAP) {
            meta[(size_t)row * 16 + 1 + local] = i;
        } else {
            int s = atomicAdd(ovf_cnt, 1);
            ovf_list[s] = i;
        }
    }
    grid_bar(bar + 1);

    // ---- phase 2: gather, grid-stride with meta prefetch ----
    const int4* meta4 = (const int4*)meta;
    int row = blockIdx.x;                  // NBLK << nrows: always valid
    int4 m0 = meta4[(size_t)row * 4 + 0];
    int4 m1 = meta4[(size_t)row * 4 + 1];
    int4 m2 = meta4[(size_t)row * 4 + 2];
    int4 m3 = meta4[(size_t)row * 4 + 3];
    while (row < nrows) {
        int nxt = row + NBLK;
        int n_raw = m0.x;
        int n = n_raw > CAP ? CAP : n_raw;
        int g[CAP] = {m0.y, m0.z, m0.w,
                      m1.x, m1.y, m1.z, m1.w,
                      m2.x, m2.y, m2.z, m2.w,
                      m3.x, m3.y, m3.z, m3.w};

        // Issue all grad loads (independent -> high MLP), nontemporal.
        f4 v[CAP];
        #pragma unroll
        for (int k = 0; k < CAP; ++k)
            if (k < n) v[k] = __builtin_nontemporal_load(&grad[(size_t)g[k] * C4 + tid]);

        // Prefetch next row's meta line while grad loads are in flight.
        if (nxt < nrows) {
            m0 = meta4[(size_t)nxt * 4 + 0];
            m1 = meta4[(size_t)nxt * 4 + 1];
            m2 = meta4[(size_t)nxt * 4 + 2];
            m3 = meta4[(size_t)nxt * 4 + 3];
        }

        f4 acc = {0.f, 0.f, 0.f, 0.f};
        #pragma unroll
        for (int k = 0; k < CAP; ++k)
            if (k < n) acc += v[k];

        // Rare path: row overflowed CAP (empty for benchmark distribution).
        if (n_raw > CAP) {
            int no = *ovf_cnt;
            for (int e = 0; e < no; ++e) {
                int i = ovf_list[e];
                if (idx[i] == row)
                    acc += __builtin_nontemporal_load(&grad[(size_t)i * C4 + tid]);
            }
        }

        __builtin_nontemporal_store(acc, &out[(size_t)row * C4 + tid]);
        row = nxt;
    }
}

// Fallback (R1 kernel) if workspace is too small.
__global__ __launch_bounds__(256) void scatter_atomic_kernel(
    const float4* __restrict__ grad, const int* __restrict__ idx,
    float* __restrict__ out, int n_idx) {
    int row = blockIdx.x;
    if (row >= n_idx) return;
    int c4 = threadIdx.x;
    int target = idx[row];
    float4 v = grad[(size_t)row * C4 + c4];
    float* o = out + (size_t)target * NCOLS + (size_t)c4 * 4;
    atomicAdd(o + 0, v.x);
    atomicAdd(o + 1, v.y);
    atomicAdd(o + 2, v.z);
    atomicAdd(o + 3, v.w);
}

extern "C" void kernel_launch(void* const* d_in, const int* in_sizes, int n_in,
                              void* d_out, int out_size, void* d_ws, size_t ws_size,
                              hipStream_t stream) {
    const f4* grad = (const f4*)d_in[0];
    const int* idx = (const int*)d_in[1];
    f4* out = (f4*)d_out;

    int n_idx = in_sizes[1];               // 131072
    int nrows = out_size / NCOLS;          // 50000

    size_t need = ((size_t)nrows * 16 + 1 + n_idx + 2) * sizeof(int);
    if (ws_size < need) {
        // Fallback: atomic scatter (R1 path).
        hipMemsetAsync(d_out, 0, (size_t)out_size * sizeof(float), stream);
        scatter_atomic_kernel<<<n_idx, 256, 0, stream>>>(
            (const float4*)d_in[0], idx, (float*)d_out, n_idx);
        return;
    }

    int* meta     = (int*)d_ws;            // [nrows][16]: {cnt, slot[0..14]}
    int* ovf_cnt  = meta + (size_t)nrows * 16;      // [1]
    int* ovf_list = ovf_cnt + 1;                    // [n_idx]
    int* bar      = ovf_list + n_idx;               // [2] barrier counters

    // Zero only the two barrier counters; meta is zeroed in-kernel (phase 0).
    hipMemsetAsync(bar, 0, 2 * sizeof(int), stream);

    fused_kernel<<<NBLK, NTHR, 0, stream>>>(grad, idx, meta, ovf_list,
                                            ovf_cnt, bar, out, n_idx, nrows);
}

// Round 8
// 147.217 us; speedup vs baseline: 2.3634x; 2.3634x over previous
//
#include <hip/hip_runtime.h>
#include <hip/hip_bf16.h>

// Gather backward / scatter-add:
//   out = zeros(50000, 1024); out[indices[i], :] += grad_last[i, :]
//
// R5 (145 µs, proven): memset(3.2MB meta) -> fill -> gather(1 block/row).
// R6/R7 fusion attempts both lost: fusing gather into a grid-stride loop made
// the compiler minimize VGPRs (48) and serialize the 15-deep load batch ->
// MLP ~1 -> 348 µs. Block-turnover parallelism + the standalone gather's
// register-held load batch are the asset; don't touch them.
//
// R8 = R5 with fill vectorized: each fill thread loads int4 of indices
// (4x fewer idx load instrs / blocks; 4 independent atomics pipeline).

#define NCOLS 1024
#define C4 (NCOLS / 4)
#define CAP 15            // slots per 64B meta line (16 ints: cnt + 15 slots)

typedef float f4 __attribute__((ext_vector_type(4)));

__global__ void fill_kernel(const int4* __restrict__ idx4, int* __restrict__ meta,
                            int* __restrict__ ovf_list, int* __restrict__ ovf_cnt,
                            int n4) {
    int t = blockIdx.x * blockDim.x + threadIdx.x;
    if (t >= n4) return;
    int4 r = idx4[t];
    int base = t * 4;
    #pragma unroll
    for (int j = 0; j < 4; ++j) {
        int row = (j == 0) ? r.x : (j == 1) ? r.y : (j == 2) ? r.z : r.w;
        int i = base + j;
        int local = atomicAdd(&meta[(size_t)row * 16], 1);
        if (local < CAP) {
            meta[(size_t)row * 16 + 1 + local] = i;
        } else {
            int s = atomicAdd(ovf_cnt, 1);
            ovf_list[s] = i;
        }
    }
}

__global__ __launch_bounds__(256) void gather_kernel(
    const f4* __restrict__ grad, const int4* __restrict__ meta4,
    const int* __restrict__ idx, const int* __restrict__ ovf_list,
    const int* __restrict__ ovf_cnt, f4* __restrict__ out) {
    int row = blockIdx.x;
    int tid = threadIdx.x;                 // 0..255, one float4 each

    // One 64B meta line: 4 parallel int4 loads (same addr across block ->
    // broadcast).
    int4 m0 = meta4[(size_t)row * 4 + 0];
    int4 m1 = meta4[(size_t)row * 4 + 1];
    int4 m2 = meta4[(size_t)row * 4 + 2];
    int4 m3 = meta4[(size_t)row * 4 + 3];
    int n_raw = m0.x;
    int n = n_raw > CAP ? CAP : n_raw;
    int g[CAP] = {m0.y, m0.z, m0.w,
                  m1.x, m1.y, m1.z, m1.w,
                  m2.x, m2.y, m2.z, m2.w,
                  m3.x, m3.y, m3.z, m3.w};

    // Phase 1: issue all grad loads (independent -> high MLP). Nontemporal:
    // touch-once stream, don't pollute L2.
    f4 v[CAP];
    #pragma unroll
    for (int k = 0; k < CAP; ++k)
        if (k < n) v[k] = __builtin_nontemporal_load(&grad[(size_t)g[k] * C4 + tid]);

    // Phase 2: accumulate.
    f4 acc = {0.f, 0.f, 0.f, 0.f};
    #pragma unroll
    for (int k = 0; k < CAP; ++k)
        if (k < n) acc += v[k];

    // Rare path: this row overflowed CAP. Scan the overflow list for our
    // entries (ovf is empty for the benchmark distribution; correctness net).
    if (n_raw > CAP) {
        int no = *ovf_cnt;
        for (int e = 0; e < no; ++e) {
            int i = ovf_list[e];
            if (idx[i] == row)
                acc += __builtin_nontemporal_load(&grad[(size_t)i * C4 + tid]);
        }
    }

    __builtin_nontemporal_store(acc, &out[(size_t)row * C4 + tid]);
}

// Fallback (R1 kernel) if workspace is too small.
__global__ __launch_bounds__(256) void scatter_atomic_kernel(
    const float4* __restrict__ grad, const int* __restrict__ idx,
    float* __restrict__ out, int n_idx) {
    int row = blockIdx.x;
    if (row >= n_idx) return;
    int c4 = threadIdx.x;
    int target = idx[row];
    float4 v = grad[(size_t)row * C4 + c4];
    float* o = out + (size_t)target * NCOLS + (size_t)c4 * 4;
    atomicAdd(o + 0, v.x);
    atomicAdd(o + 1, v.y);
    atomicAdd(o + 2, v.z);
    atomicAdd(o + 3, v.w);
}

extern "C" void kernel_launch(void* const* d_in, const int* in_sizes, int n_in,
                              void* d_out, int out_size, void* d_ws, size_t ws_size,
                              hipStream_t stream) {
    const f4* grad = (const f4*)d_in[0];
    const int* idx = (const int*)d_in[1];

    int n_idx = in_sizes[1];               // 131072 (multiple of 4)
    int nrows = out_size / NCOLS;          // 50000

    size_t need = ((size_t)nrows * 16 + 1 + n_idx) * sizeof(int);
    if (ws_size < need || (n_idx & 3) != 0) {
        // Fallback: atomic scatter (R1 path).
        hipMemsetAsync(d_out, 0, (size_t)out_size * sizeof(float), stream);
        scatter_atomic_kernel<<<n_idx, 256, 0, stream>>>(
            (const float4*)d_in[0], idx, (float*)d_out, n_idx);
        return;
    }

    int* meta     = (int*)d_ws;            // [nrows][16]: {cnt, slot[0..14]}
    int* ovf_cnt  = meta + (size_t)nrows * 16;      // [1]
    int* ovf_list = ovf_cnt + 1;                    // [n_idx]

    // Zero meta (cnt fields) + ovf_cnt in one contiguous memset (~3.2 MB).
    hipMemsetAsync(meta, 0, ((size_t)nrows * 16 + 1) * sizeof(int), stream);

    int n4 = n_idx / 4;
    int blk = 256;
    fill_kernel<<<(n4 + blk - 1) / blk, blk, 0, stream>>>(
        (const int4*)idx, meta, ovf_list, ovf_cnt, n4);
    gather_kernel<<<nrows, 256, 0, stream>>>(grad, (const int4*)meta,
                                             idx, ovf_list, ovf_cnt,
                                             (f4*)d_out);
}